// Round 7
// baseline (152.752 us; speedup 1.0000x reference)
//
#include <hip/hip_runtime.h>
#include <hip/hip_bf16.h>
#include <stdint.h>

// LePEAttention — coalesced staging + swizzled tiles + MFMA rsum + slim regs.
// B=4, C=64, H=W=128, heads=8, hd=8, window=128x2 (256 toks).
// Grid 512: bid = ((b*8 + head)*2 + wjh)*8 + x  (x = XCD pin).
// Block = (b, head: 8ch, x, wjh: 4 windows), 512 threads = 8 waves:
// wave w -> window (w&3), q-half (w>>2).
// Register diet for TRUE 6 waves/SIMD (3 blocks/CU, cap 85 VGPR):
//   - kf[16] stays in VGPRs (k_s is overlaid by rpe, must be cached);
//   - vf[] array DELETED: V fragment read from v_t inside the T-loop.
//     v_t is never overwritten. Lane-routed base pointer: lr<8 -> channel
//     row, lr==8 -> LDS ones row (keeps MFMA-rsum), lr>8 -> zeros row.
//     An empty asm on the pointer per qg blocks LICM from re-materializing
//     the 32-reg array (which caused R6's scratch spill: WRITE_SIZE 16->42MB).
// Q/K/rpe tiles: [4 win][256 tok][16B] with XOR swizzle
//   byte = tok*16 ^ ((tok>>4 & 7)<<4).
// rsum via MFMA: V A-row 8 = bf16 1.0 -> PV acc row 8 = sum(exp), free on
// the matrix pipe; denominator broadcast via one __shfl.
// Math: S^T via mfma_16x16x16 (A=K,B=Q, hd=8, quads 2-3 zero) -> exp2 ->
// pack feeds PV mfma_16x16x16 B-operand directly (layout identity).

typedef __attribute__((ext_vector_type(4))) short bf16x4;
typedef __attribute__((ext_vector_type(4))) float f32x4;

static __device__ __forceinline__ uint32_t pk2(float x, float y) {
    union { __hip_bfloat162 h2; uint32_t u; } c;
    c.h2 = __float22bfloat162_rn(make_float2(x, y));
    return c.u;
}
static __device__ __forceinline__ float bflo(uint32_t u){ return __uint_as_float(u<<16); }
static __device__ __forceinline__ float bfhi(uint32_t u){ return __uint_as_float(u & 0xffff0000u); }

// 8-byte LDS read at 4-byte alignment guarantee.
static __device__ __forceinline__ uint2 ld2(const char* p) {
    uint2 r;
    r.x = *(const uint32_t*)(p);
    r.y = *(const uint32_t*)(p + 4);
    return r;
}

// Swizzled byte offset of token row in a Q/K/rpe tile (16B payload rows).
static __device__ __forceinline__ int qk_off(int tok) {
    return (tok * 16) ^ ((tok >> 4 & 7) << 4);
}

static __device__ __forceinline__ f32x4 mfma16x16x16bf16(bf16x4 a, bf16x4 b, f32x4 c) {
#if __has_builtin(__builtin_amdgcn_mfma_f32_16x16x16bf16_1k)
    return __builtin_amdgcn_mfma_f32_16x16x16bf16_1k(a, b, c, 0, 0, 0);
#else
    f32x4 d;
    asm volatile("v_mfma_f32_16x16x16_bf16 %0, %1, %2, %3\n\ts_nop 7\n\ts_nop 7"
                 : "=v"(d) : "v"(a), "v"(b), "v"(c));
    return d;
#endif
}

// LDS layout (51568 B):
//   q_s:  [4 win][4128B: 256 tok x 16B swizzled + 32B pad]   16512 B @ 0
//   k_s:  same; later rpe bf16 same layout                   16512 B @ 16512
//   v_t:  [4 win][8 ch][536B], tok t at byte 2t+4            17152 B @ 33024
//   cw_s: 72 conv w + 8 bias                                   320 B @ 50176
//   ones: 536 B of bf16 1.0                                         @ 50496
//   zero: 536 B of 0                                                @ 51032
#define QK_WIN_STR 4128
#define V_CH_STR   536
#define V_WIN_STR  4288
#define ONES_OFF   50496
#define ZERO_OFF   51032

__global__ __launch_bounds__(512, 6)
void lepe_attn(const float* __restrict__ temp,
               const float* __restrict__ conv_w,
               const float* __restrict__ conv_b,
               float* __restrict__ out)
{
    __shared__ __align__(16) char smem[51568];
    char* q_s = smem;
    char* k_s = smem + 16512;
    char* v_t = smem + 33024;
    float* cw_s = (float*)(smem + 50176);

    const int tid  = threadIdx.x;
    const int wave = tid >> 6, lane = tid & 63;
    const int lr = lane & 15, quad = lane >> 4;
    const int win   = wave & 3;          // window within the wjh quartet
    const int qbase = (wave >> 2) * 8;   // q-half: qg 0-7 or 8-15

    const int bid = blockIdx.x;
    const int x  = bid & 7;
    int t_ = bid >> 3;
    const int wjh  = t_ & 1;  t_ >>= 1;
    const int head = t_ & 7;
    const int b    = t_ >> 3;
    const int wi   = x*8 + wjh*4 + win;  // this wave's window index

    const size_t cstr = 16384, sstr = 64 * cstr;
    const float qs = 0.35355339059327373f * 1.4426950408889634f;  // hd^-0.5 * log2e

    // ---- staging: wave = channel (0..7); lane -> (h-group, 32B-half) ----
    {
        const int cg = wave;                 // channel within head
        const int hg = lane >> 1, hf1 = lane & 1;
        const int w0 = hf1 * 2;              // local window of this float4
        const float* bp = temp + (size_t)b*3*sstr + (size_t)(head*8 + cg)*cstr
                        + x*16 + wjh*8 + hf1*4;
        #pragma unroll
        for (int i = 0; i < 4; ++i) {
            int h = i*32 + hg;
            int o0 = qk_off(2*h), o1 = qk_off(2*h + 1);
            float4 fq = *(const float4*)(bp + (size_t)h*128);
            uint32_t a0 = pk2(fq.x*qs, fq.y*qs);
            uint32_t a1 = pk2(fq.z*qs, fq.w*qs);
            *(uint16_t*)(q_s + w0*QK_WIN_STR     + o0 + cg*2) = (uint16_t)a0;
            *(uint16_t*)(q_s + w0*QK_WIN_STR     + o1 + cg*2) = (uint16_t)(a0>>16);
            *(uint16_t*)(q_s + (w0+1)*QK_WIN_STR + o0 + cg*2) = (uint16_t)a1;
            *(uint16_t*)(q_s + (w0+1)*QK_WIN_STR + o1 + cg*2) = (uint16_t)(a1>>16);
            float4 fk = *(const float4*)(bp + sstr + (size_t)h*128);
            uint32_t b0 = pk2(fk.x, fk.y);
            uint32_t b1 = pk2(fk.z, fk.w);
            *(uint16_t*)(k_s + w0*QK_WIN_STR     + o0 + cg*2) = (uint16_t)b0;
            *(uint16_t*)(k_s + w0*QK_WIN_STR     + o1 + cg*2) = (uint16_t)(b0>>16);
            *(uint16_t*)(k_s + (w0+1)*QK_WIN_STR + o0 + cg*2) = (uint16_t)b1;
            *(uint16_t*)(k_s + (w0+1)*QK_WIN_STR + o1 + cg*2) = (uint16_t)(b1>>16);
            float4 fv = *(const float4*)(bp + 2*sstr + (size_t)h*128);
            *(uint32_t*)(v_t + w0*V_WIN_STR     + cg*V_CH_STR + 4*h + 4) = pk2(fv.x, fv.y);
            *(uint32_t*)(v_t + (w0+1)*V_WIN_STR + cg*V_CH_STR + 4*h + 4) = pk2(fv.z, fv.w);
        }
        if (tid < 72) cw_s[tid] = conv_w[head*72 + tid];
        if (tid < 8)  cw_s[72 + tid] = conv_b[head*8 + tid];
        if (tid < 32) {
            int vw = tid >> 3, vc = tid & 7;
            *(uint32_t*)(v_t + vw*V_WIN_STR + vc*V_CH_STR)       = 0;   // toks -2,-1
            *(uint32_t*)(v_t + vw*V_WIN_STR + vc*V_CH_STR + 516) = 0;   // toks 256,257
        }
        // ones / zeros rows for lane-routed V reads (268 dwords total)
        if (tid < 268) {
            ((uint32_t*)(smem + ONES_OFF))[tid] = (tid < 134) ? 0x3F803F80u : 0u;
        }
    }
    __syncthreads();

    // ---- preload K A-frags into VGPRs (k_s gets overlaid by rpe next) ----
    const f32x4 zf = {0.f, 0.f, 0.f, 0.f};
    const uint2 z2 = make_uint2(0, 0);
    uint2 kf[16];
    #pragma unroll
    for (int T = 0; T < 16; ++T) {
        uint2 kk = ld2(k_s + win*QK_WIN_STR + qk_off(T*16 + lr) + (quad & 1)*8);
        kf[T] = (quad < 2) ? kk : z2;
    }
    // lane-routed V base: lr<8 -> channel row, lr==8 -> ones, lr>8 -> zeros.
    const char* vbase0;
    {
        const char* row = (lr < 8) ? (v_t + win*V_WIN_STR + lr*V_CH_STR)
                        : ((lr == 8) ? (smem + ONES_OFF) : (smem + ZERO_OFF));
        vbase0 = row + 4 + quad*8;
    }
    __syncthreads();   // all K frags read; k_s region now free for rpe

    // ---- rpe = depthwise 3x3 conv of V (window-local), bf16 into k_s ----
    {
        const int w2  = tid >> 7;            // window 0..3
        const int chl = (tid >> 4) & 7;      // channel 0..7
        const int seg = tid & 15;            // 16 toks per thread
        const char* base = v_t + w2*V_WIN_STR + chl*V_CH_STR + seg*32;  // toks seg*16-2 .. +17
        uint32_t d[10];                      // base 8-aligned
        *(uint2*)(d+0) = *(const uint2*)(base);
        *(uint2*)(d+2) = *(const uint2*)(base+8);
        *(uint2*)(d+4) = *(const uint2*)(base+16);
        *(uint2*)(d+6) = *(const uint2*)(base+24);
        *(uint2*)(d+8) = *(const uint2*)(base+32);
        float w9[9];
        #pragma unroll
        for (int k = 0; k < 9; ++k) w9[k] = cw_s[chl*9 + k];
        const float bia = cw_s[72 + chl];
        #pragma unroll
        for (int tt = 0; tt < 16; ++tt) {
            int tok = seg*16 + tt;
            int w01 = tok & 1;
            int L = (tt >> 1) * 2;           // taps = local bf16 idx L..L+5
            float rp = bia;
            #pragma unroll
            for (int dy = 0; dy < 3; ++dy) {
                #pragma unroll
                for (int wp = 0; wp < 2; ++wp) {
                    int idx = L + 2*dy + wp;
                    uint32_t dw = d[idx >> 1];
                    float tap = (idx & 1) ? bfhi(dw) : bflo(dw);
                    rp = fmaf(w9[dy*3 + wp + 1 - w01], tap, rp);
                }
            }
            union { __hip_bfloat16 h; uint16_t u; } cv;
            cv.h = __float2bfloat16(rp);
            *(uint16_t*)(k_s + w2*QK_WIN_STR + qk_off(tok) + chl*2) = cv.u;
        }
    }
    __syncthreads();

    // ---- main: per q-group: S^T mfma -> exp -> pack -> PV mfma (chained) ----
    #pragma unroll 1
    for (int qg0 = 0; qg0 < 8; ++qg0) {
        const int qg = qbase + qg0;
        uint2 qq = ld2(q_s + win*QK_WIN_STR + qk_off(qg*16 + lr) + (quad & 1)*8);
        union { uint2 u; bf16x4 h4; } qf; qf.u = (quad < 2) ? qq : z2;
        // launder V base: blocks LICM from hoisting the 16 qg-invariant
        // V-frag loads into a 32-reg array (R6's spill).
        const char* vb = vbase0;
        asm volatile("" : "+v"(vb));
        f32x4 acc = zf;
        #pragma unroll
        for (int T = 0; T < 16; ++T) {
            union { uint2 u; bf16x4 h4; } vfu; vfu.u = ld2(vb + T*32);
            union { uint2 u; bf16x4 h4; } kfu; kfu.u = kf[T];
            f32x4 sc = mfma16x16x16bf16(kfu.h4, qf.h4, zf);
            float e0 = __builtin_amdgcn_exp2f(sc[0]);
            float e1 = __builtin_amdgcn_exp2f(sc[1]);
            float e2 = __builtin_amdgcn_exp2f(sc[2]);
            float e3 = __builtin_amdgcn_exp2f(sc[3]);
            union { uint2 u; bf16x4 h4; } pb; pb.u = make_uint2(pk2(e0,e1), pk2(e2,e3));
            acc = mfma16x16x16bf16(vfu.h4, pb.h4, acc);
        }
        // sum(exp) landed in acc[0] of quad-2 lanes (PV D row 8), col = lr.
        float rs = __shfl(acc[0], 32 + lr);
        const float rinv = __builtin_amdgcn_rcpf(rs);
        if (quad < 2) {
            int tok = qg*16 + lr;
            int h = tok >> 1, w01 = tok & 1;
            uint2 rp2 = ld2(k_s + win*QK_WIN_STR + qk_off(tok) + quad*8);
            float4 ov;
            ov.x = fmaf(acc[0], rinv, bflo(rp2.x));
            ov.y = fmaf(acc[1], rinv, bfhi(rp2.x));
            ov.z = fmaf(acc[2], rinv, bflo(rp2.y));
            ov.w = fmaf(acc[3], rinv, bfhi(rp2.y));
            size_t addr = (size_t)b*1048576 + (size_t)(h*128 + wi*2 + w01)*64
                        + head*8 + quad*4;
            *(float4*)(out + addr) = ov;
        }
    }
}

extern "C" void kernel_launch(void* const* d_in, const int* in_sizes, int n_in,
                              void* d_out, int out_size, void* d_ws, size_t ws_size,
                              hipStream_t stream) {
    const float* temp = (const float*)d_in[0];
    const float* cw   = (const float*)d_in[1];
    const float* cb   = (const float*)d_in[2];
    float* o = (float*)d_out;
    (void)in_sizes; (void)n_in; (void)out_size; (void)d_ws; (void)ws_size;
    lepe_attn<<<dim3(512), dim3(512), 0, stream>>>(temp, cw, cb, o);
}

// Round 8
// 116.128 us; speedup vs baseline: 1.3154x; 1.3154x over previous
//
#include <hip/hip_runtime.h>
#include <hip/hip_bf16.h>
#include <stdint.h>

// LePEAttention — R5 register structure + swizzle + MFMA-rsum + dual acc.
// B=4, C=64, H=W=128, heads=8, hd=8, window=128x2 (256 toks).
// Grid 512: bid = ((b*8 + head)*2 + wjh)*8 + x  (x = XCD pin).
// Block = (b, head: 8ch, x, wjh: 4 windows), 512 threads = 8 waves:
// wave w -> window (w&3), q-half (w>>2).
// PROVEN-BEST STRUCTURE (R5, 46.6us): kf[16] AND vf[16] cached in VGPRs,
// inner loop has ZERO LDS ops. (R6: reg-cap 85 -> scratch spill, 59us.
// R7: V loads in T-loop -> lgkmcnt serialization in the mfma chain, 82us.)
// launch_bounds(512,4): VGPR cap 128, ~60 used, no spill; 2 blocks/CU.
// Adds on top of R5:
//  - Q/K/rpe tiles [4 win][256 tok][16B] XOR-swizzled:
//    byte = tok*16 ^ ((tok>>4 & 7)<<4)  (rpe writes were 16-way conflicted
//    at stride 20; R5 SQ_LDS_BANK_CONFLICT 2.17M -> expect <0.8M).
//  - MFMA rsum: V A-row 8 (lr==8) = bf16 1.0 -> PV acc row 8 = sum(exp)
//    on the matrix pipe; deletes the VALU rsum chain (~400 adds/thread).
//  - Dual PV accumulators (even/odd T) halve the serial acc-dependency
//    chain of 16 back-to-back PV MFMAs.
// Math: S^T via mfma_16x16x16 (A=K,B=Q, hd=8, quads 2-3 zero) -> exp2 ->
// pack feeds PV mfma_16x16x16 B-operand directly (layout identity).

typedef __attribute__((ext_vector_type(4))) short bf16x4;
typedef __attribute__((ext_vector_type(4))) float f32x4;

static __device__ __forceinline__ uint32_t pk2(float x, float y) {
    union { __hip_bfloat162 h2; uint32_t u; } c;
    c.h2 = __float22bfloat162_rn(make_float2(x, y));
    return c.u;
}
static __device__ __forceinline__ float bflo(uint32_t u){ return __uint_as_float(u<<16); }
static __device__ __forceinline__ float bfhi(uint32_t u){ return __uint_as_float(u & 0xffff0000u); }

// 8-byte LDS read at 4-byte alignment guarantee.
static __device__ __forceinline__ uint2 ld2(const char* p) {
    uint2 r;
    r.x = *(const uint32_t*)(p);
    r.y = *(const uint32_t*)(p + 4);
    return r;
}

// Swizzled byte offset of token row in a Q/K/rpe tile (16B payload rows).
static __device__ __forceinline__ int qk_off(int tok) {
    return (tok * 16) ^ ((tok >> 4 & 7) << 4);
}

static __device__ __forceinline__ f32x4 mfma16x16x16bf16(bf16x4 a, bf16x4 b, f32x4 c) {
#if __has_builtin(__builtin_amdgcn_mfma_f32_16x16x16bf16_1k)
    return __builtin_amdgcn_mfma_f32_16x16x16bf16_1k(a, b, c, 0, 0, 0);
#else
    f32x4 d;
    asm volatile("v_mfma_f32_16x16x16_bf16 %0, %1, %2, %3\n\ts_nop 7\n\ts_nop 7"
                 : "=v"(d) : "v"(a), "v"(b), "v"(c));
    return d;
#endif
}

// LDS layout (50496 B):
//   q_s:  [4 win][4128B: 256 tok x 16B swizzled + 32B pad]   16512 B @ 0
//   k_s:  same; later rpe bf16 same layout                   16512 B @ 16512
//   v_t:  [4 win][8 ch][536B], tok t at byte 2t+4            17152 B @ 33024
//   cw_s: 72 conv w + 8 bias                                   320 B @ 50176
#define QK_WIN_STR 4128
#define V_CH_STR   536
#define V_WIN_STR  4288

__global__ __launch_bounds__(512, 4)
void lepe_attn(const float* __restrict__ temp,
               const float* __restrict__ conv_w,
               const float* __restrict__ conv_b,
               float* __restrict__ out)
{
    __shared__ __align__(16) char smem[50496];
    char* q_s = smem;
    char* k_s = smem + 16512;
    char* v_t = smem + 33024;
    float* cw_s = (float*)(smem + 50176);

    const int tid  = threadIdx.x;
    const int wave = tid >> 6, lane = tid & 63;
    const int lr = lane & 15, quad = lane >> 4;
    const int win   = wave & 3;          // window within the wjh quartet
    const int qbase = (wave >> 2) * 8;   // q-half: qg 0-7 or 8-15

    const int bid = blockIdx.x;
    const int x  = bid & 7;
    int t_ = bid >> 3;
    const int wjh  = t_ & 1;  t_ >>= 1;
    const int head = t_ & 7;
    const int b    = t_ >> 3;
    const int wi   = x*8 + wjh*4 + win;  // this wave's window index

    const size_t cstr = 16384, sstr = 64 * cstr;
    const float qs = 0.35355339059327373f * 1.4426950408889634f;  // hd^-0.5 * log2e

    // ---- staging: wave = channel (0..7); lane -> (h-group, 32B-half) ----
    {
        const int cg = wave;                 // channel within head
        const int hg = lane >> 1, hf1 = lane & 1;
        const int w0 = hf1 * 2;              // local window of this float4
        const float* bp = temp + (size_t)b*3*sstr + (size_t)(head*8 + cg)*cstr
                        + x*16 + wjh*8 + hf1*4;
        #pragma unroll
        for (int i = 0; i < 4; ++i) {
            int h = i*32 + hg;
            int o0 = qk_off(2*h), o1 = qk_off(2*h + 1);
            float4 fq = *(const float4*)(bp + (size_t)h*128);
            uint32_t a0 = pk2(fq.x*qs, fq.y*qs);
            uint32_t a1 = pk2(fq.z*qs, fq.w*qs);
            *(uint16_t*)(q_s + w0*QK_WIN_STR     + o0 + cg*2) = (uint16_t)a0;
            *(uint16_t*)(q_s + w0*QK_WIN_STR     + o1 + cg*2) = (uint16_t)(a0>>16);
            *(uint16_t*)(q_s + (w0+1)*QK_WIN_STR + o0 + cg*2) = (uint16_t)a1;
            *(uint16_t*)(q_s + (w0+1)*QK_WIN_STR + o1 + cg*2) = (uint16_t)(a1>>16);
            float4 fk = *(const float4*)(bp + sstr + (size_t)h*128);
            uint32_t b0 = pk2(fk.x, fk.y);
            uint32_t b1 = pk2(fk.z, fk.w);
            *(uint16_t*)(k_s + w0*QK_WIN_STR     + o0 + cg*2) = (uint16_t)b0;
            *(uint16_t*)(k_s + w0*QK_WIN_STR     + o1 + cg*2) = (uint16_t)(b0>>16);
            *(uint16_t*)(k_s + (w0+1)*QK_WIN_STR + o0 + cg*2) = (uint16_t)b1;
            *(uint16_t*)(k_s + (w0+1)*QK_WIN_STR + o1 + cg*2) = (uint16_t)(b1>>16);
            float4 fv = *(const float4*)(bp + 2*sstr + (size_t)h*128);
            *(uint32_t*)(v_t + w0*V_WIN_STR     + cg*V_CH_STR + 4*h + 4) = pk2(fv.x, fv.y);
            *(uint32_t*)(v_t + (w0+1)*V_WIN_STR + cg*V_CH_STR + 4*h + 4) = pk2(fv.z, fv.w);
        }
        if (tid < 72) cw_s[tid] = conv_w[head*72 + tid];
        if (tid < 8)  cw_s[72 + tid] = conv_b[head*8 + tid];
        if (tid < 32) {
            int vw = tid >> 3, vc = tid & 7;
            *(uint32_t*)(v_t + vw*V_WIN_STR + vc*V_CH_STR)       = 0;   // toks -2,-1
            *(uint32_t*)(v_t + vw*V_WIN_STR + vc*V_CH_STR + 516) = 0;   // toks 256,257
        }
    }
    __syncthreads();

    // ---- preload K A-frags and V A-frags into VGPRs ----
    const f32x4 zf = {0.f, 0.f, 0.f, 0.f};
    const uint2 z2 = make_uint2(0, 0);
    const uint2 ones2 = make_uint2(0x3F803F80u, 0x3F803F80u);  // 4x bf16 1.0
    uint2 kf[16]; uint2 vf[16];
    #pragma unroll
    for (int T = 0; T < 16; ++T) {
        uint2 kk = ld2(k_s + win*QK_WIN_STR + qk_off(T*16 + lr) + (quad & 1)*8);
        kf[T] = (quad < 2) ? kk : z2;
        uint2 vv = ld2(v_t + win*V_WIN_STR + (lane & 7)*V_CH_STR + 4 + (T*16 + quad*4)*2);
        // row 8 = ones channel: PV acc row 8 accumulates sum(exp) per q-col.
        vf[T] = (lr < 8) ? vv : ((lr == 8) ? ones2 : z2);
    }
    __syncthreads();   // all K frags read; k_s region now free for rpe

    // ---- rpe = depthwise 3x3 conv of V (window-local), bf16 into k_s ----
    {
        const int w2  = tid >> 7;            // window 0..3
        const int chl = (tid >> 4) & 7;      // channel 0..7
        const int seg = tid & 15;            // 16 toks per thread
        const char* base = v_t + w2*V_WIN_STR + chl*V_CH_STR + seg*32;  // toks seg*16-2 .. +17
        uint32_t d[10];                      // base 8-aligned
        *(uint2*)(d+0) = *(const uint2*)(base);
        *(uint2*)(d+2) = *(const uint2*)(base+8);
        *(uint2*)(d+4) = *(const uint2*)(base+16);
        *(uint2*)(d+6) = *(const uint2*)(base+24);
        *(uint2*)(d+8) = *(const uint2*)(base+32);
        float w9[9];
        #pragma unroll
        for (int k = 0; k < 9; ++k) w9[k] = cw_s[chl*9 + k];
        const float bia = cw_s[72 + chl];
        #pragma unroll
        for (int tt = 0; tt < 16; ++tt) {
            int tok = seg*16 + tt;
            int w01 = tok & 1;
            int L = (tt >> 1) * 2;           // taps = local bf16 idx L..L+5
            float rp = bia;
            #pragma unroll
            for (int dy = 0; dy < 3; ++dy) {
                #pragma unroll
                for (int wp = 0; wp < 2; ++wp) {
                    int idx = L + 2*dy + wp;
                    uint32_t dw = d[idx >> 1];
                    float tap = (idx & 1) ? bfhi(dw) : bflo(dw);
                    rp = fmaf(w9[dy*3 + wp + 1 - w01], tap, rp);
                }
            }
            union { __hip_bfloat16 h; uint16_t u; } cv;
            cv.h = __float2bfloat16(rp);
            *(uint16_t*)(k_s + w2*QK_WIN_STR + qk_off(tok) + chl*2) = cv.u;
        }
    }
    __syncthreads();

    // ---- main: per q-group: S^T mfma -> exp -> pack -> PV mfma (chained) ----
    #pragma unroll 1
    for (int qg0 = 0; qg0 < 8; ++qg0) {
        const int qg = qbase + qg0;
        uint2 qq = ld2(q_s + win*QK_WIN_STR + qk_off(qg*16 + lr) + (quad & 1)*8);
        union { uint2 u; bf16x4 h4; } qf; qf.u = (quad < 2) ? qq : z2;
        f32x4 acc0 = zf, acc1 = zf;   // dual acc: halves the PV dep chain
        #pragma unroll
        for (int T = 0; T < 16; T += 2) {
            union { uint2 u; bf16x4 h4; } kfu0; kfu0.u = kf[T];
            union { uint2 u; bf16x4 h4; } kfu1; kfu1.u = kf[T+1];
            f32x4 sc0 = mfma16x16x16bf16(kfu0.h4, qf.h4, zf);
            f32x4 sc1 = mfma16x16x16bf16(kfu1.h4, qf.h4, zf);
            float a0 = __builtin_amdgcn_exp2f(sc0[0]);
            float a1 = __builtin_amdgcn_exp2f(sc0[1]);
            float a2 = __builtin_amdgcn_exp2f(sc0[2]);
            float a3 = __builtin_amdgcn_exp2f(sc0[3]);
            float b0_ = __builtin_amdgcn_exp2f(sc1[0]);
            float b1_ = __builtin_amdgcn_exp2f(sc1[1]);
            float b2_ = __builtin_amdgcn_exp2f(sc1[2]);
            float b3_ = __builtin_amdgcn_exp2f(sc1[3]);
            union { uint2 u; bf16x4 h4; } pb0; pb0.u = make_uint2(pk2(a0,a1), pk2(a2,a3));
            union { uint2 u; bf16x4 h4; } pb1; pb1.u = make_uint2(pk2(b0_,b1_), pk2(b2_,b3_));
            union { uint2 u; bf16x4 h4; } vf0; vf0.u = vf[T];
            union { uint2 u; bf16x4 h4; } vf1; vf1.u = vf[T+1];
            acc0 = mfma16x16x16bf16(vf0.h4, pb0.h4, acc0);
            acc1 = mfma16x16x16bf16(vf1.h4, pb1.h4, acc1);
        }
        f32x4 acc;
        acc[0] = acc0[0] + acc1[0];
        acc[1] = acc0[1] + acc1[1];
        acc[2] = acc0[2] + acc1[2];
        acc[3] = acc0[3] + acc1[3];
        // sum(exp) is acc[0] of quad-2 lanes (PV D row 8), col = lr.
        float rs = __shfl(acc[0], 32 + lr);
        const float rinv = __builtin_amdgcn_rcpf(rs);
        if (quad < 2) {
            int tok = qg*16 + lr;
            int h = tok >> 1, w01 = tok & 1;
            uint2 rp2 = ld2(k_s + win*QK_WIN_STR + qk_off(tok) + quad*8);
            float4 ov;
            ov.x = fmaf(acc[0], rinv, bflo(rp2.x));
            ov.y = fmaf(acc[1], rinv, bfhi(rp2.x));
            ov.z = fmaf(acc[2], rinv, bflo(rp2.y));
            ov.w = fmaf(acc[3], rinv, bfhi(rp2.y));
            size_t addr = (size_t)b*1048576 + (size_t)(h*128 + wi*2 + w01)*64
                        + head*8 + quad*4;
            *(float4*)(out + addr) = ov;
        }
    }
}

extern "C" void kernel_launch(void* const* d_in, const int* in_sizes, int n_in,
                              void* d_out, int out_size, void* d_ws, size_t ws_size,
                              hipStream_t stream) {
    const float* temp = (const float*)d_in[0];
    const float* cw   = (const float*)d_in[1];
    const float* cb   = (const float*)d_in[2];
    float* o = (float*)d_out;
    (void)in_sizes; (void)n_in; (void)out_size; (void)d_ws; (void)ws_size;
    lepe_attn<<<dim3(512), dim3(512), 0, stream>>>(temp, cw, cb, o);
}

// Round 9
// 112.803 us; speedup vs baseline: 1.3542x; 1.0295x over previous
//
#include <hip/hip_runtime.h>
#include <hip/hip_bf16.h>
#include <stdint.h>

// LePEAttention — 4-wave residency quantum (2-window blocks).
// B=4, C=64, H=W=128, heads=8, hd=8, window=128x2 (256 toks).
// Grid 1024: bid = ((b*8 + head)*4 + wq)*8 + x  (x = XCD pin; wq siblings
// share 64B lines on the same XCD's L2). Block = 256 thr = 4 waves:
// wave w -> window (w&1), q-half (w>>1). Window wi = x*8 + wq*2 + win.
// WHY: R8 showed OccupancyPercent 26.6% = ~8.5 waves/CU = ONE 8-wave block
// resident (true regs = 56 VGPR + 64 AGPR for kf/vf ~ 120-136 > 128 ->
// second 8-wave block can't fit). 4-wave blocks + 25.4KB LDS -> 4 blocks/CU
// (16 waves) even at the same per-wave register footprint.
// Math pipeline unchanged from R8 (43.3us): kf[16]+vf[16] in regs, zero-LDS
// inner loop, XOR-swizzled Q/K/rpe tiles, MFMA-rsum (V A-row 8 = 1.0 ->
// denominator on the matrix pipe), dual PV accumulators.
// S^T via mfma_16x16x16 (A=K,B=Q, hd=8, quads 2-3 zero) -> exp2 -> pack
// feeds PV mfma_16x16x16 B-operand directly (layout identity).

typedef __attribute__((ext_vector_type(4))) short bf16x4;
typedef __attribute__((ext_vector_type(4))) float f32x4;

static __device__ __forceinline__ uint32_t pk2(float x, float y) {
    union { __hip_bfloat162 h2; uint32_t u; } c;
    c.h2 = __float22bfloat162_rn(make_float2(x, y));
    return c.u;
}
static __device__ __forceinline__ float bflo(uint32_t u){ return __uint_as_float(u<<16); }
static __device__ __forceinline__ float bfhi(uint32_t u){ return __uint_as_float(u & 0xffff0000u); }

// 8-byte LDS read at 4-byte alignment guarantee.
static __device__ __forceinline__ uint2 ld2(const char* p) {
    uint2 r;
    r.x = *(const uint32_t*)(p);
    r.y = *(const uint32_t*)(p + 4);
    return r;
}

// Swizzled byte offset of token row in a Q/K/rpe tile (16B payload rows).
static __device__ __forceinline__ int qk_off(int tok) {
    return (tok * 16) ^ ((tok >> 4 & 7) << 4);
}

static __device__ __forceinline__ f32x4 mfma16x16x16bf16(bf16x4 a, bf16x4 b, f32x4 c) {
#if __has_builtin(__builtin_amdgcn_mfma_f32_16x16x16bf16_1k)
    return __builtin_amdgcn_mfma_f32_16x16x16bf16_1k(a, b, c, 0, 0, 0);
#else
    f32x4 d;
    asm volatile("v_mfma_f32_16x16x16_bf16 %0, %1, %2, %3\n\ts_nop 7\n\ts_nop 7"
                 : "=v"(d) : "v"(a), "v"(b), "v"(c));
    return d;
#endif
}

// LDS layout (25408 B):
//   q_s:  [2 win][4128B: 256 tok x 16B swizzled + 32B pad]    8256 B @ 0
//   k_s:  same; later rpe bf16 same layout                    8256 B @ 8256
//   v_t:  [2 win][8 ch][536B], tok t at byte 2t+4             8576 B @ 16512
//   cw_s: 72 conv w + 8 bias                                   320 B @ 25088
#define QK_WIN_STR 4128
#define V_CH_STR   536
#define V_WIN_STR  4288

__global__ __launch_bounds__(256, 4)
void lepe_attn(const float* __restrict__ temp,
               const float* __restrict__ conv_w,
               const float* __restrict__ conv_b,
               float* __restrict__ out)
{
    __shared__ __align__(16) char smem[25408];
    char* q_s = smem;
    char* k_s = smem + 8256;
    char* v_t = smem + 16512;
    float* cw_s = (float*)(smem + 25088);

    const int tid  = threadIdx.x;
    const int wave = tid >> 6, lane = tid & 63;
    const int lr = lane & 15, quad = lane >> 4;
    const int win   = wave & 1;          // window within the wq pair
    const int qbase = (wave >> 1) * 8;   // q-half: qg 0-7 or 8-15

    const int bid = blockIdx.x;
    const int x  = bid & 7;
    int t_ = bid >> 3;
    const int wq   = t_ & 3;  t_ >>= 2;
    const int head = t_ & 7;
    const int b    = t_ >> 3;
    const int wi   = x*8 + wq*2 + win;   // this wave's window index

    const size_t cstr = 16384, sstr = 64 * cstr;
    const float qs = 0.35355339059327373f * 1.4426950408889634f;  // hd^-0.5 * log2e

    // ---- staging: thread r = i*256+tid -> (ch = r>>7, h = r&127) ----
    {
        #pragma unroll
        for (int i = 0; i < 4; ++i) {
            int r  = i*256 + tid;
            int ch = r >> 7;             // 0..7
            int h  = r & 127;
            const float* bp = temp + (size_t)b*3*sstr + (size_t)(head*8 + ch)*cstr
                            + (size_t)h*128 + x*16 + wq*4;
            int o0 = qk_off(2*h), o1 = qk_off(2*h + 1);
            float4 fq = *(const float4*)(bp);
            uint32_t a0 = pk2(fq.x*qs, fq.y*qs);   // win0: toks 2h, 2h+1
            uint32_t a1 = pk2(fq.z*qs, fq.w*qs);   // win1
            *(uint16_t*)(q_s + o0 + ch*2)              = (uint16_t)a0;
            *(uint16_t*)(q_s + o1 + ch*2)              = (uint16_t)(a0>>16);
            *(uint16_t*)(q_s + QK_WIN_STR + o0 + ch*2) = (uint16_t)a1;
            *(uint16_t*)(q_s + QK_WIN_STR + o1 + ch*2) = (uint16_t)(a1>>16);
            float4 fk = *(const float4*)(bp + sstr);
            uint32_t b0 = pk2(fk.x, fk.y);
            uint32_t b1 = pk2(fk.z, fk.w);
            *(uint16_t*)(k_s + o0 + ch*2)              = (uint16_t)b0;
            *(uint16_t*)(k_s + o1 + ch*2)              = (uint16_t)(b0>>16);
            *(uint16_t*)(k_s + QK_WIN_STR + o0 + ch*2) = (uint16_t)b1;
            *(uint16_t*)(k_s + QK_WIN_STR + o1 + ch*2) = (uint16_t)(b1>>16);
            float4 fv = *(const float4*)(bp + 2*sstr);
            *(uint32_t*)(v_t + ch*V_CH_STR + 4*h + 4)             = pk2(fv.x, fv.y);
            *(uint32_t*)(v_t + V_WIN_STR + ch*V_CH_STR + 4*h + 4) = pk2(fv.z, fv.w);
        }
        if (tid < 72) cw_s[tid] = conv_w[head*72 + tid];
        if (tid < 8)  cw_s[72 + tid] = conv_b[head*8 + tid];
        if (tid < 16) {
            int vw = tid >> 3, vc = tid & 7;
            *(uint32_t*)(v_t + vw*V_WIN_STR + vc*V_CH_STR)       = 0;   // toks -2,-1
            *(uint32_t*)(v_t + vw*V_WIN_STR + vc*V_CH_STR + 516) = 0;   // toks 256,257
        }
    }
    __syncthreads();

    // ---- preload K A-frags and V A-frags into VGPRs ----
    const f32x4 zf = {0.f, 0.f, 0.f, 0.f};
    const uint2 z2 = make_uint2(0, 0);
    const uint2 ones2 = make_uint2(0x3F803F80u, 0x3F803F80u);  // 4x bf16 1.0
    uint2 kf[16]; uint2 vf[16];
    #pragma unroll
    for (int T = 0; T < 16; ++T) {
        uint2 kk = ld2(k_s + win*QK_WIN_STR + qk_off(T*16 + lr) + (quad & 1)*8);
        kf[T] = (quad < 2) ? kk : z2;
        uint2 vv = ld2(v_t + win*V_WIN_STR + (lane & 7)*V_CH_STR + 4 + (T*16 + quad*4)*2);
        // row 8 = ones channel: PV acc row 8 accumulates sum(exp) per q-col.
        vf[T] = (lr < 8) ? vv : ((lr == 8) ? ones2 : z2);
    }
    __syncthreads();   // all K frags read; k_s region now free for rpe

    // ---- rpe = depthwise 3x3 conv of V (window-local), bf16 into k_s ----
    {
        const int w2  = tid >> 7;            // window 0..1
        const int chl = (tid >> 4) & 7;      // channel 0..7
        const int seg = tid & 15;            // 16 toks per thread
        const char* base = v_t + w2*V_WIN_STR + chl*V_CH_STR + seg*32;  // toks seg*16-2 .. +17
        uint32_t d[10];                      // base 8-aligned
        *(uint2*)(d+0) = *(const uint2*)(base);
        *(uint2*)(d+2) = *(const uint2*)(base+8);
        *(uint2*)(d+4) = *(const uint2*)(base+16);
        *(uint2*)(d+6) = *(const uint2*)(base+24);
        *(uint2*)(d+8) = *(const uint2*)(base+32);
        float w9[9];
        #pragma unroll
        for (int k = 0; k < 9; ++k) w9[k] = cw_s[chl*9 + k];
        const float bia = cw_s[72 + chl];
        #pragma unroll
        for (int tt = 0; tt < 16; ++tt) {
            int tok = seg*16 + tt;
            int w01 = tok & 1;
            int L = (tt >> 1) * 2;           // taps = local bf16 idx L..L+5
            float rp = bia;
            #pragma unroll
            for (int dy = 0; dy < 3; ++dy) {
                #pragma unroll
                for (int wp = 0; wp < 2; ++wp) {
                    int idx = L + 2*dy + wp;
                    uint32_t dw = d[idx >> 1];
                    float tap = (idx & 1) ? bfhi(dw) : bflo(dw);
                    rp = fmaf(w9[dy*3 + wp + 1 - w01], tap, rp);
                }
            }
            union { __hip_bfloat16 h; uint16_t u; } cv;
            cv.h = __float2bfloat16(rp);
            *(uint16_t*)(k_s + w2*QK_WIN_STR + qk_off(tok) + chl*2) = cv.u;
        }
    }
    __syncthreads();

    // ---- main: per q-group: S^T mfma -> exp -> pack -> PV mfma (chained) ----
    #pragma unroll 1
    for (int qg0 = 0; qg0 < 8; ++qg0) {
        const int qg = qbase + qg0;
        uint2 qq = ld2(q_s + win*QK_WIN_STR + qk_off(qg*16 + lr) + (quad & 1)*8);
        union { uint2 u; bf16x4 h4; } qf; qf.u = (quad < 2) ? qq : z2;
        f32x4 acc0 = zf, acc1 = zf;   // dual acc: halves the PV dep chain
        #pragma unroll
        for (int T = 0; T < 16; T += 2) {
            union { uint2 u; bf16x4 h4; } kfu0; kfu0.u = kf[T];
            union { uint2 u; bf16x4 h4; } kfu1; kfu1.u = kf[T+1];
            f32x4 sc0 = mfma16x16x16bf16(kfu0.h4, qf.h4, zf);
            f32x4 sc1 = mfma16x16x16bf16(kfu1.h4, qf.h4, zf);
            float a0 = __builtin_amdgcn_exp2f(sc0[0]);
            float a1 = __builtin_amdgcn_exp2f(sc0[1]);
            float a2 = __builtin_amdgcn_exp2f(sc0[2]);
            float a3 = __builtin_amdgcn_exp2f(sc0[3]);
            float b0_ = __builtin_amdgcn_exp2f(sc1[0]);
            float b1_ = __builtin_amdgcn_exp2f(sc1[1]);
            float b2_ = __builtin_amdgcn_exp2f(sc1[2]);
            float b3_ = __builtin_amdgcn_exp2f(sc1[3]);
            union { uint2 u; bf16x4 h4; } pb0; pb0.u = make_uint2(pk2(a0,a1), pk2(a2,a3));
            union { uint2 u; bf16x4 h4; } pb1; pb1.u = make_uint2(pk2(b0_,b1_), pk2(b2_,b3_));
            union { uint2 u; bf16x4 h4; } vf0; vf0.u = vf[T];
            union { uint2 u; bf16x4 h4; } vf1; vf1.u = vf[T+1];
            acc0 = mfma16x16x16bf16(vf0.h4, pb0.h4, acc0);
            acc1 = mfma16x16x16bf16(vf1.h4, pb1.h4, acc1);
        }
        f32x4 acc;
        acc[0] = acc0[0] + acc1[0];
        acc[1] = acc0[1] + acc1[1];
        acc[2] = acc0[2] + acc1[2];
        acc[3] = acc0[3] + acc1[3];
        // sum(exp) is acc[0] of quad-2 lanes (PV D row 8), col = lr.
        float rs = __shfl(acc[0], 32 + lr);
        const float rinv = __builtin_amdgcn_rcpf(rs);
        if (quad < 2) {
            int tok = qg*16 + lr;
            int h = tok >> 1, w01 = tok & 1;
            uint2 rp2 = ld2(k_s + win*QK_WIN_STR + qk_off(tok) + quad*8);
            float4 ov;
            ov.x = fmaf(acc[0], rinv, bflo(rp2.x));
            ov.y = fmaf(acc[1], rinv, bfhi(rp2.x));
            ov.z = fmaf(acc[2], rinv, bflo(rp2.y));
            ov.w = fmaf(acc[3], rinv, bfhi(rp2.y));
            size_t addr = (size_t)b*1048576 + (size_t)(h*128 + wi*2 + w01)*64
                        + head*8 + quad*4;
            *(float4*)(out + addr) = ov;
        }
    }
}

extern "C" void kernel_launch(void* const* d_in, const int* in_sizes, int n_in,
                              void* d_out, int out_size, void* d_ws, size_t ws_size,
                              hipStream_t stream) {
    const float* temp = (const float*)d_in[0];
    const float* cw   = (const float*)d_in[1];
    const float* cb   = (const float*)d_in[2];
    float* o = (float*)d_out;
    (void)in_sizes; (void)n_in; (void)out_size; (void)d_ws; (void)ws_size;
    lepe_attn<<<dim3(1024), dim3(256), 0, stream>>>(temp, cw, cb, o);
}